// Round 4
// baseline (170.461 us; speedup 1.0000x reference)
//
#include <hip/hip_runtime.h>

#define N_NODES 100000
#define N_EDGES 1000000
#define D 64
#define N_GRAPHS 512
#define DOT_THREADS (N_NODES * 16)   // 16 threads per node
#define K2_BLOCKS 256
#define K2_THREADS 1024

// K1: y[v] = dot(x[v,:], W)  (16 threads/node, float4 each)
//     + tail threads: zero acc/counter and compute inv_cnt[g] via binary
//       search on the sorted batch array (runs concurrently on spare CUs).
__global__ __launch_bounds__(256) void dot_kernel(const float* __restrict__ x,
                                                  const float* __restrict__ W,
                                                  const int* __restrict__ batch,
                                                  float* __restrict__ y,
                                                  float* __restrict__ acc,
                                                  float* __restrict__ inv_cnt,
                                                  unsigned int* __restrict__ counter) {
    int t = blockIdx.x * blockDim.x + threadIdx.x;
    if (t < DOT_THREADS) {
        int v = t >> 4;      // node index
        int sub = t & 15;    // 16 sub-lanes cover 64 floats via float4
        const float4 xv = *reinterpret_cast<const float4*>(x + (size_t)v * D + sub * 4);
        const float4 wv = *reinterpret_cast<const float4*>(W + sub * 4);
        float p = xv.x * wv.x + xv.y * wv.y + xv.z * wv.z + xv.w * wv.w;
        p += __shfl_xor(p, 1, 64);
        p += __shfl_xor(p, 2, 64);
        p += __shfl_xor(p, 4, 64);
        p += __shfl_xor(p, 8, 64);
        if (sub == 0) y[v] = p;
        return;
    }
    int g = t - DOT_THREADS;
    if (g >= N_GRAPHS) return;
    if (g == 0) *counter = 0u;
    acc[g] = 0.0f;
    // counts[g] = lower_bound(batch, g+1) - lower_bound(batch, g)
    int lo0 = 0, hi0 = N_NODES;
    while (lo0 < hi0) { int mid = (lo0 + hi0) >> 1; if (batch[mid] < g) lo0 = mid + 1; else hi0 = mid; }
    int lo1 = 0, hi1 = N_NODES;
    while (lo1 < hi1) { int mid = (lo1 + hi1) >> 1; if (batch[mid] < g + 1) lo1 = mid + 1; else hi1 = mid; }
    float cnt = (float)(hi1 - lo0);
    inv_cnt[g] = 1.0f / fmaxf(cnt, 1.0f);
}

// K2: per-block LDS histogram of edge_attr[e]*y[src_e] into graph bins,
//     flush to acc with device-scope atomics, last block finalizes out[].
__global__ __launch_bounds__(K2_THREADS) void edge_kernel(const int* __restrict__ ei,
                                                          const float* __restrict__ ea,
                                                          const int* __restrict__ batch,
                                                          const float* __restrict__ y,
                                                          const float* __restrict__ inv_cnt,
                                                          const float* __restrict__ bptr,
                                                          float* __restrict__ acc,
                                                          unsigned int* __restrict__ counter,
                                                          float* __restrict__ out) {
    __shared__ float sacc[N_GRAPHS];
    __shared__ int is_last;
    const int tid = threadIdx.x;
    if (tid < N_GRAPHS) sacc[tid] = 0.0f;
    __syncthreads();

    // 4 edges per thread via 16B loads; 250000 vec-edges <= 262144 threads
    int idx = blockIdx.x * K2_THREADS + tid;
    if (idx < N_EDGES / 4) {
        const int4   s4 = reinterpret_cast<const int4*>(ei)[idx];
        const int4   d4 = reinterpret_cast<const int4*>(ei + N_EDGES)[idx];
        const float4 a4 = reinterpret_cast<const float4*>(ea)[idx];
        // 4 independent gather pairs -> ILP hides L2 latency
        float m0 = a4.x * y[s4.x];  int g0 = batch[d4.x];
        float m1 = a4.y * y[s4.y];  int g1 = batch[d4.y];
        float m2 = a4.z * y[s4.z];  int g2 = batch[d4.z];
        float m3 = a4.w * y[s4.w];  int g3 = batch[d4.w];
        atomicAdd(&sacc[g0], m0);
        atomicAdd(&sacc[g1], m1);
        atomicAdd(&sacc[g2], m2);
        atomicAdd(&sacc[g3], m3);
    }
    __syncthreads();
    if (tid < N_GRAPHS) {
        float v = sacc[tid];
        if (v != 0.0f) atomicAdd(&acc[tid], v);
    }
    __threadfence();          // order this thread's flush before counter bump
    __syncthreads();          // all threads' fences complete
    if (tid == 0) {
        unsigned int old = __hip_atomic_fetch_add(counter, 1u, __ATOMIC_ACQ_REL,
                                                  __HIP_MEMORY_SCOPE_AGENT);
        is_last = (old == (unsigned int)(gridDim.x - 1));
    }
    __syncthreads();
    if (is_last) {
        __threadfence();
        if (tid < N_GRAPHS) {
            float v = __hip_atomic_load(&acc[tid], __ATOMIC_RELAXED,
                                        __HIP_MEMORY_SCOPE_AGENT);
            out[tid] = v * inv_cnt[tid] + bptr[0];
        }
    }
}

extern "C" void kernel_launch(void* const* d_in, const int* in_sizes, int n_in,
                              void* d_out, int out_size, void* d_ws, size_t ws_size,
                              hipStream_t stream) {
    const float* x     = (const float*)d_in[0];  // [N, 64] fp32
    const int*   ei    = (const int*)  d_in[1];  // [2, E] int32
    const float* ea    = (const float*)d_in[2];  // [E] fp32
    const int*   batch = (const int*)  d_in[3];  // [N] int32, sorted
    const float* W     = (const float*)d_in[4];  // [1, 64] fp32
    const float* b     = (const float*)d_in[5];  // [1] fp32
    float* out = (float*)d_out;                  // [G, 1] = 512 fp32

    float* y        = (float*)d_ws;              // N_NODES floats
    float* acc      = y + N_NODES;               // N_GRAPHS floats
    float* inv_cnt  = acc + N_GRAPHS;            // N_GRAPHS floats
    unsigned int* counter = (unsigned int*)(inv_cnt + N_GRAPHS);

    // K1: 1,600,000 dot threads + 512 tail threads
    dot_kernel<<<(DOT_THREADS + N_GRAPHS + 255) / 256, 256, 0, stream>>>(
        x, W, batch, y, acc, inv_cnt, counter);
    // K2: 256 blocks x 1024 threads, last block writes out
    edge_kernel<<<K2_BLOCKS, K2_THREADS, 0, stream>>>(
        ei, ea, batch, y, inv_cnt, b, acc, counter, out);
}

// Round 5
// 106.071 us; speedup vs baseline: 1.6071x; 1.6071x over previous
//
#include <hip/hip_runtime.h>

#define N_NODES 100000
#define N_EDGES 1000000
#define D 64
#define N_GRAPHS 512
#define DOT_THREADS (N_NODES * 16)   // 16 threads per node
#define K2_BLOCKS 256
#define K2_THREADS 1024

// K1: y[v] = dot(x[v,:], W)  (16 threads/node, float4 each)
//     + 512 tail threads: zero acc and compute inv_cnt[g] via binary search
//       on the sorted batch array (hidden under K1's 25.6 MB stream).
__global__ __launch_bounds__(256) void dot_kernel(const float* __restrict__ x,
                                                  const float* __restrict__ W,
                                                  const int* __restrict__ batch,
                                                  float* __restrict__ y,
                                                  float* __restrict__ acc,
                                                  float* __restrict__ inv_cnt) {
    int t = blockIdx.x * blockDim.x + threadIdx.x;
    if (t < DOT_THREADS) {
        int v = t >> 4;      // node index
        int sub = t & 15;    // 16 sub-lanes cover 64 floats via float4
        const float4 xv = *reinterpret_cast<const float4*>(x + (size_t)v * D + sub * 4);
        const float4 wv = *reinterpret_cast<const float4*>(W + sub * 4);
        float p = xv.x * wv.x + xv.y * wv.y + xv.z * wv.z + xv.w * wv.w;
        p += __shfl_xor(p, 1, 64);
        p += __shfl_xor(p, 2, 64);
        p += __shfl_xor(p, 4, 64);
        p += __shfl_xor(p, 8, 64);
        if (sub == 0) y[v] = p;
        return;
    }
    int g = t - DOT_THREADS;
    if (g >= N_GRAPHS) return;
    acc[g] = 0.0f;
    // counts[g] = lower_bound(batch, g+1) - lower_bound(batch, g)
    int lo0 = 0, hi0 = N_NODES;
    while (lo0 < hi0) { int mid = (lo0 + hi0) >> 1; if (batch[mid] < g) lo0 = mid + 1; else hi0 = mid; }
    int lo1 = 0, hi1 = N_NODES;
    while (lo1 < hi1) { int mid = (lo1 + hi1) >> 1; if (batch[mid] < g + 1) lo1 = mid + 1; else hi1 = mid; }
    float cnt = (float)(hi1 - lo0);
    inv_cnt[g] = 1.0f / fmaxf(cnt, 1.0f);
}

// K2: per-block LDS histogram of edge_attr[e]*y[src_e] into graph bins,
//     flush with one global atomic per (block, bin). NO fences/counters —
//     device-scope fence machinery cost 76 us in round 4.
__global__ __launch_bounds__(K2_THREADS) void edge_kernel(const int* __restrict__ ei,
                                                          const float* __restrict__ ea,
                                                          const int* __restrict__ batch,
                                                          const float* __restrict__ y,
                                                          float* __restrict__ acc) {
    __shared__ float sacc[N_GRAPHS];
    const int tid = threadIdx.x;
    if (tid < N_GRAPHS) sacc[tid] = 0.0f;
    __syncthreads();

    // 4 edges per thread via 16B loads; 250000 vec-edges <= 262144 threads
    int idx = blockIdx.x * K2_THREADS + tid;
    if (idx < N_EDGES / 4) {
        const int4   s4 = reinterpret_cast<const int4*>(ei)[idx];
        const int4   d4 = reinterpret_cast<const int4*>(ei + N_EDGES)[idx];
        const float4 a4 = reinterpret_cast<const float4*>(ea)[idx];
        // 4 independent gather pairs -> ILP hides L2 latency
        float m0 = a4.x * y[s4.x];  int g0 = batch[d4.x];
        float m1 = a4.y * y[s4.y];  int g1 = batch[d4.y];
        float m2 = a4.z * y[s4.z];  int g2 = batch[d4.z];
        float m3 = a4.w * y[s4.w];  int g3 = batch[d4.w];
        atomicAdd(&sacc[g0], m0);
        atomicAdd(&sacc[g1], m1);
        atomicAdd(&sacc[g2], m2);
        atomicAdd(&sacc[g3], m3);
    }
    __syncthreads();
    if (tid < N_GRAPHS) {
        float v = sacc[tid];
        if (v != 0.0f) atomicAdd(&acc[tid], v);
    }
}

// K3: out[g] = acc[g] * inv_cnt[g] + b   (one tiny block, launch-bound)
__global__ __launch_bounds__(512) void final_kernel(const float* __restrict__ acc,
                                                    const float* __restrict__ inv_cnt,
                                                    const float* __restrict__ bptr,
                                                    float* __restrict__ out) {
    int g = threadIdx.x;
    out[g] = acc[g] * inv_cnt[g] + bptr[0];
}

extern "C" void kernel_launch(void* const* d_in, const int* in_sizes, int n_in,
                              void* d_out, int out_size, void* d_ws, size_t ws_size,
                              hipStream_t stream) {
    const float* x     = (const float*)d_in[0];  // [N, 64] fp32
    const int*   ei    = (const int*)  d_in[1];  // [2, E] int32
    const float* ea    = (const float*)d_in[2];  // [E] fp32
    const int*   batch = (const int*)  d_in[3];  // [N] int32, sorted
    const float* W     = (const float*)d_in[4];  // [1, 64] fp32
    const float* b     = (const float*)d_in[5];  // [1] fp32
    float* out = (float*)d_out;                  // [G, 1] = 512 fp32

    float* y       = (float*)d_ws;               // N_NODES floats
    float* acc     = y + N_NODES;                // N_GRAPHS floats
    float* inv_cnt = acc + N_GRAPHS;             // N_GRAPHS floats

    // K1: 1,600,000 dot threads + 512 tail threads (zeroes acc, computes inv_cnt)
    dot_kernel<<<(DOT_THREADS + N_GRAPHS + 255) / 256, 256, 0, stream>>>(
        x, W, batch, y, acc, inv_cnt);
    // K2: 256 blocks x 1024 threads
    edge_kernel<<<K2_BLOCKS, K2_THREADS, 0, stream>>>(ei, ea, batch, y, acc);
    // K3: finalize
    final_kernel<<<1, 512, 0, stream>>>(acc, inv_cnt, b, out);
}